// Round 6
// baseline (316.089 us; speedup 1.0000x reference)
//
#include <hip/hip_runtime.h>

typedef unsigned short u16;
typedef unsigned int u32;
typedef float f32x4 __attribute__((ext_vector_type(4)));
typedef __bf16 bf16x8 __attribute__((ext_vector_type(8)));

// f32 -> bf16 round-to-nearest-even (scalar)
__device__ __forceinline__ u16 f2bf(float f) {
  unsigned u = __float_as_uint(f);
  unsigned r = u + 0x7fffu + ((u >> 16) & 1u);
  return (u16)(r >> 16);
}
// packed f32 pair -> 2x bf16 in one u32 (lo = first arg)
__device__ __forceinline__ u32 cvt_pk_bf16(float lo, float hi) {
  u32 r;
  asm("v_cvt_pk_bf16_f32 %0, %1, %2" : "=v"(r) : "v"(lo), "v"(hi));
  return r;
}
// hardware 2^x
__device__ __forceinline__ float exp2_hw(float x) {
  float r;
  asm("v_exp_f32 %0, %1" : "=v"(r) : "v"(x));
  return r;
}
__device__ __forceinline__ bf16x8 f32x8_to_bf16x8(float4 a, float4 b) {
  union { u32 u[4]; bf16x8 v; } t;
  t.u[0] = cvt_pk_bf16(a.x, a.y);
  t.u[1] = cvt_pk_bf16(a.z, a.w);
  t.u[2] = cvt_pk_bf16(b.x, b.y);
  t.u[3] = cvt_pk_bf16(b.z, b.w);
  return t.v;
}

// 1/sqrt(32) * log2(e)  — softmax scale folded with exp->exp2 conversion
#define QSCALE 0.25513936f

// ---------------------------------------------------------------------------
// proj_kv: fused pooled K+V (round-3/5-verified KV path). grid 128, block 256.
// Layouts: Kt[b][s][32], Vb[b][ch][4096].
// ---------------------------------------------------------------------------
__global__ __launch_bounds__(256) void proj_kv(
    const float* __restrict__ x, const float* __restrict__ Wk, const float* __restrict__ bk,
    const float* __restrict__ Wv, const float* __restrict__ bv, u16* __restrict__ Kt,
    u16* __restrict__ Vb) {
  __shared__ __align__(16) u16 xs[16384];  // pooled [64 s][256 c] bf16, swizzled (32KB)
  const int tid = threadIdx.x;
  const int lane = tid & 63, w = tid >> 6;
  const int l15 = lane & 15, l4 = lane >> 4;
  const int bi = blockIdx.x;
  const int b = bi >> 6, sy = bi & 63;
  const float* xb = x + (size_t)b * 256 * 16384;
  const f32x4 zero = {0.f, 0.f, 0.f, 0.f};

  // pooled stage: xs[s][c] = mean2x2
#pragma unroll
  for (int rr = 0; rr < 4; ++rr) {
    int c = rr * 64 + (tid >> 2);
    int f4base = (tid & 3) * 8;
    const float* r0 = xb + (size_t)c * 16384 + (size_t)sy * 256;
#pragma unroll
    for (int u = 0; u < 8; ++u) {
      int jj = f4base + u;
      float4 a = *reinterpret_cast<const float4*>(r0 + jj * 4);
      float4 d = *reinterpret_cast<const float4*>(r0 + 128 + jj * 4);
      float p0 = (a.x + a.y + d.x + d.y) * 0.25f;
      float p1 = (a.z + a.w + d.z + d.w) * 0.25f;
      int s0 = jj * 2;
      *reinterpret_cast<u16*>((char*)xs + (s0 + 0) * 512 + (((c >> 3) ^ ((s0 + 0) & 7)) * 16) + (c & 7) * 2) = f2bf(p0);
      *reinterpret_cast<u16*>((char*)xs + (s0 + 1) * 512 + (((c >> 3) ^ ((s0 + 1) & 7)) * 16) + (c & 7) * 2) = f2bf(p1);
    }
  }
  __syncthreads();

  // GEMM: wave w = n-tile (16 s). m-tiles: 0..1 = K (32 oc), 2..17 = V (256 oc)
  f32x4 acc[18];
#pragma unroll
  for (int m = 0; m < 18; ++m) acc[m] = zero;
  const int sl = w * 16 + l15;
#pragma unroll
  for (int k = 0; k < 8; ++k) {
    bf16x8 bf = *reinterpret_cast<const bf16x8*>((char*)xs + sl * 512 +
                                                 (((k * 4 + l4) ^ (sl & 7)) * 16));
#pragma unroll
    for (int m = 0; m < 2; ++m) {
      const float* wr = Wk + (size_t)(m * 16 + l15) * 256 + k * 32 + l4 * 8;
      float4 fa = *reinterpret_cast<const float4*>(wr);
      float4 fb = *reinterpret_cast<const float4*>(wr + 4);
      acc[m] = __builtin_amdgcn_mfma_f32_16x16x32_bf16(f32x8_to_bf16x8(fa, fb), bf, acc[m], 0, 0, 0);
    }
#pragma unroll
    for (int m = 0; m < 16; ++m) {
      const float* wr = Wv + (size_t)(m * 16 + l15) * 256 + k * 32 + l4 * 8;
      float4 fa = *reinterpret_cast<const float4*>(wr);
      float4 fb = *reinterpret_cast<const float4*>(wr + 4);
      acc[2 + m] = __builtin_amdgcn_mfma_f32_16x16x32_bf16(f32x8_to_bf16x8(fa, fb), bf, acc[2 + m], 0, 0, 0);
    }
  }
  // K store (packed): Kt[b][s][oc]
#pragma unroll
  for (int m = 0; m < 2; ++m) {
    int oc0 = m * 16 + l4 * 4;
    u32 p0 = cvt_pk_bf16(acc[m][0] + bk[oc0], acc[m][1] + bk[oc0 + 1]);
    u32 p1 = cvt_pk_bf16(acc[m][2] + bk[oc0 + 2], acc[m][3] + bk[oc0 + 3]);
    u16* dst = Kt + ((size_t)b * 4096 + sy * 64 + sl) * 32 + oc0;
    *reinterpret_cast<u32*>(dst) = p0;
    *reinterpret_cast<u32*>(dst + 2) = p1;
  }
  // V store: Vb[b][oc][s]
#pragma unroll
  for (int m = 0; m < 16; ++m) {
#pragma unroll
    for (int r = 0; r < 4; ++r) {
      int oc = m * 16 + l4 * 4 + r;
      Vb[((size_t)b * 256 + oc) * 4096 + sy * 64 + sl] = f2bf(acc[2 + m][r] + bv[oc]);
    }
  }
}

// ---------------------------------------------------------------------------
// attn v6: wave-independent k-loop (ZERO barriers, ZERO LDS in the loop).
// Block = 64 tokens; wave = 32 tokens x 128 channels (th = w>>1, chh = w&1).
// Each wave computes full QK for its tokens (S^T = mfma(K,Q), 8 MFMA over 64
// keys), softmax in-register, then transposes P to the PV A-fragment layout
// with v_permlane32_swap + v_permlane16_swap (verified element mapping), and
// runs PV (16 MFMA) with V fragments loaded at iteration top from L2.
// Q-projection is fused at kernel start (block-private, via LDS).
// ---------------------------------------------------------------------------
__global__ __launch_bounds__(256, 2) void attn_kernel(
    const float* __restrict__ x, const float* __restrict__ Wq, const float* __restrict__ bq,
    const u16* __restrict__ Kt, const u16* __restrict__ Vb, const float* __restrict__ gamma,
    float* __restrict__ out) {
  __shared__ __align__(16) u16 smem[26624];  // 52KB: xt 32KB | wq 16KB | q_lds 4KB
  u16* xt = smem;            // [64 t][256 c] bf16, swizzled
  u16* wqs = smem + 16384;   // [32 oc][256 c] bf16, swizzled, pre-scaled
  u16* qlds = smem + 24576;  // [64 t][32 oc] bf16 (Qb layout)

  const int tid = threadIdx.x;
  const int lane = tid & 63, w = tid >> 6;
  const int l15 = lane & 15, l4 = lane >> 4;
  const int raw = blockIdx.x;              // 0..511
  const int xcd = raw & 7, loc = raw >> 3; // loc 0..63
  const int b = xcd >> 2;
  const int t0 = ((xcd & 3) * 64 + loc) * 64;
  const f32x4 zero = {0.f, 0.f, 0.f, 0.f};

  // ================= fused Q projection (round-3/5-verified) =================
  {
    const float* xp = x + (size_t)b * 256 * 16384 + t0;
    // stage Wq (scale folded)
    for (int i = tid; i < 4096; i += 256) {
      int oc = i >> 7, c0 = (i & 127) * 2;
      float2 f = *reinterpret_cast<const float2*>(Wq + oc * 256 + c0);
      u32 pk = cvt_pk_bf16(f.x * QSCALE, f.y * QSCALE);
      *reinterpret_cast<u32*>((char*)wqs + oc * 512 + (((c0 >> 3) ^ (oc & 7)) * 16) +
                              (c0 & 7) * 2) = pk;
    }
    // stage x tile transposed: xt[t][c]
#pragma unroll
    for (int rr = 0; rr < 4; ++rr) {
      int c = rr * 64 + (tid >> 2);
      int tch = (tid & 3) * 16;
      const float* src = xp + (size_t)c * 16384 + tch;
#pragma unroll
      for (int u = 0; u < 4; ++u) {
        float4 f = *reinterpret_cast<const float4*>(src + u * 4);
        int t = tch + u * 4;
        *reinterpret_cast<u16*>((char*)xt + (t + 0) * 512 + (((c >> 3) ^ ((t + 0) & 7)) * 16) + (c & 7) * 2) = f2bf(f.x);
        *reinterpret_cast<u16*>((char*)xt + (t + 1) * 512 + (((c >> 3) ^ ((t + 1) & 7)) * 16) + (c & 7) * 2) = f2bf(f.y);
        *reinterpret_cast<u16*>((char*)xt + (t + 2) * 512 + (((c >> 3) ^ ((t + 2) & 7)) * 16) + (c & 7) * 2) = f2bf(f.z);
        *reinterpret_cast<u16*>((char*)xt + (t + 3) * 512 + (((c >> 3) ^ ((t + 3) & 7)) * 16) + (c & 7) * 2) = f2bf(f.w);
      }
    }
    __syncthreads();

    // GEMM: wave w owns 16 toks (tl), m = 2 oc-tiles, k = 8
    f32x4 qacc[2] = {zero, zero};
    const int tl = w * 16 + l15;
#pragma unroll
    for (int k = 0; k < 8; ++k) {
      bf16x8 bf = *reinterpret_cast<const bf16x8*>((char*)xt + tl * 512 +
                                                   (((k * 4 + l4) ^ (tl & 7)) * 16));
#pragma unroll
      for (int m = 0; m < 2; ++m) {
        int oc = m * 16 + l15;
        bf16x8 af = *reinterpret_cast<const bf16x8*>((char*)wqs + oc * 512 +
                                                     (((k * 4 + l4) ^ (oc & 7)) * 16));
        qacc[m] = __builtin_amdgcn_mfma_f32_16x16x32_bf16(af, bf, qacc[m], 0, 0, 0);
      }
    }
    // bias (scale-folded) + packed store to q_lds[t][oc]
#pragma unroll
    for (int m = 0; m < 2; ++m) {
      int oc0 = m * 16 + l4 * 4;
      u32 p0 = cvt_pk_bf16(qacc[m][0] + bq[oc0] * QSCALE, qacc[m][1] + bq[oc0 + 1] * QSCALE);
      u32 p1 = cvt_pk_bf16(qacc[m][2] + bq[oc0 + 2] * QSCALE, qacc[m][3] + bq[oc0 + 3] * QSCALE);
      u16* dst = qlds + tl * 32 + oc0;
      *reinterpret_cast<u32*>(dst) = p0;
      *reinterpret_cast<u32*>(dst + 2) = p1;
    }
  }
  __syncthreads();  // q_lds ready; last barrier in the kernel (except none after)

  // ================= wave-independent attention =================
  const int th = w >> 1, chh = w & 1;
  const int CH0 = chh * 128;
  const u16* Kp = Kt + (size_t)b * 4096 * 32;
  const u16* Vp = Vb + (size_t)b * 256 * 4096;

  // Q B-frags for this wave's 32 tokens (col = tok, k-chunk = l4)
  bf16x8 qfr[2];
#pragma unroll
  for (int mt = 0; mt < 2; ++mt)
    qfr[mt] = *reinterpret_cast<const bf16x8*>(qlds + (th * 32 + mt * 16 + l15) * 32 + l4 * 8);

  // K A-frags for key-block 0 (row = key = ka*16+l15, k-chunk = l4)
  bf16x8 kfr[4];
#pragma unroll
  for (int ka = 0; ka < 4; ++ka)
    kfr[ka] = *reinterpret_cast<const bf16x8*>(Kp + (size_t)(ka * 16 + l15) * 32 + l4 * 8);

  f32x4 acc[2][8] = {};  // [tok-tile][ch-tile]
  float lsum[2] = {};

  for (int kt = 0; kt < 64; ++kt) {
    // V fragments for this key-block, issued first (hide L2 latency under QK)
    bf16x8 vfr[2][8];
#pragma unroll
    for (int ks = 0; ks < 2; ++ks)
#pragma unroll
      for (int nt = 0; nt < 8; ++nt)
        vfr[ks][nt] = *reinterpret_cast<const bf16x8*>(
            Vp + (size_t)(CH0 + nt * 16 + l15) * 4096 + kt * 64 + ks * 32 + l4 * 8);

    // ---- QK: S^T[key][tok] for all 64 keys of this block ----
    f32x4 sfr[4][2];
#pragma unroll
    for (int ka = 0; ka < 4; ++ka)
#pragma unroll
      for (int mt = 0; mt < 2; ++mt)
        sfr[ka][mt] = __builtin_amdgcn_mfma_f32_16x16x32_bf16(kfr[ka], qfr[mt], zero, 0, 0, 0);
    // prefetch K for next block (kfr consumed)
    {
      const int ktn = kt < 63 ? kt + 1 : 63;
#pragma unroll
      for (int ka = 0; ka < 4; ++ka)
        kfr[ka] = *reinterpret_cast<const bf16x8*>(Kp + (size_t)(ktn * 64 + ka * 16 + l15) * 32 +
                                                   l4 * 8);
    }

    // ---- softmax (no max-sub; clamp makes inf impossible) + pack ----
    u32 pk[4][2][2];
#pragma unroll
    for (int ka = 0; ka < 4; ++ka)
#pragma unroll
      for (int mt = 0; mt < 2; ++mt) {
        float p0 = exp2_hw(fminf(sfr[ka][mt][0], 28.f));
        float p1 = exp2_hw(fminf(sfr[ka][mt][1], 28.f));
        float p2 = exp2_hw(fminf(sfr[ka][mt][2], 28.f));
        float p3 = exp2_hw(fminf(sfr[ka][mt][3], 28.f));
        lsum[mt] += (p0 + p1) + (p2 + p3);
        pk[ka][mt][0] = cvt_pk_bf16(p0, p1);
        pk[ka][mt][1] = cvt_pk_bf16(p2, p3);
      }

    // ---- in-register P transpose + PV ----
    // pk[ka][mt][i] at lane (l4,l15): keys ka*16+l4*4+{2i,2i+1}, token l15.
    // afr[ks][mt] word j' must hold keys ks*32+l4*8+{2j',2j'+1}, token l15.
    // permlane32_swap: X,Y -> [X.lo,Y.lo],[X.hi,Y.hi]; permlane16_swap:
    // X,Y -> [Xg0,Yg0,Xg2,Yg2],[Xg1,Yg1,Xg3,Yg3]. Composition gives
    // X' = [Xg0,Xg2,Yg0,Yg2] (words j'=i), Y' = [Xg1,Xg3,Yg1,Yg3] (j'=2+i).
#pragma unroll
    for (int ks = 0; ks < 2; ++ks) {
      bf16x8 afr[2];
#pragma unroll
      for (int mt = 0; mt < 2; ++mt) {
        union { u32 u[4]; bf16x8 v; } t;
#pragma unroll
        for (int i = 0; i < 2; ++i) {
          u32 X = pk[2 * ks][mt][i], Y = pk[2 * ks + 1][mt][i];
          asm("v_permlane32_swap_b32 %0, %1" : "+v"(X), "+v"(Y));
          asm("v_permlane16_swap_b32 %0, %1" : "+v"(X), "+v"(Y));
          t.u[i] = X;
          t.u[2 + i] = Y;
        }
        afr[mt] = t.v;
      }
#pragma unroll
      for (int mt = 0; mt < 2; ++mt)
#pragma unroll
        for (int nt = 0; nt < 8; ++nt)
          acc[mt][nt] =
              __builtin_amdgcn_mfma_f32_16x16x32_bf16(afr[mt], vfr[ks][nt], acc[mt][nt], 0, 0, 0);
    }
  }

  // ---- finalize row sums (wave-local!): combine the 4 l4-groups ----
#pragma unroll
  for (int mt = 0; mt < 2; ++mt) {
    lsum[mt] += __shfl_xor(lsum[mt], 16, 64);
    lsum[mt] += __shfl_xor(lsum[mt], 32, 64);
  }
  // lsum[mt] (all lanes) = row-sum for token th*32+mt*16+l15. acc rows are
  // tokens l4*4+r -> redistribute via shfl.
  const float g = gamma[0];
#pragma unroll
  for (int mt = 0; mt < 2; ++mt) {
    float linv[4];
#pragma unroll
    for (int r = 0; r < 4; ++r)
      linv[r] = 1.0f / __shfl(lsum[mt], l4 * 4 + r, 64);
#pragma unroll
    for (int nt = 0; nt < 8; ++nt) {
      int ch = CH0 + nt * 16 + l15;
      size_t idx = ((size_t)(b * 256 + ch)) * 16384 + t0 + th * 32 + mt * 16 + l4 * 4;
      float4 xr = *reinterpret_cast<const float4*>(x + idx);
      float4 o;
      o.x = g * acc[mt][nt][0] * linv[0] + xr.x;
      o.y = g * acc[mt][nt][1] * linv[1] + xr.y;
      o.z = g * acc[mt][nt][2] * linv[2] + xr.z;
      o.w = g * acc[mt][nt][3] * linv[3] + xr.w;
      *reinterpret_cast<float4*>(out + idx) = o;
    }
  }
}

// ---------------------------------------------------------------------------
extern "C" void kernel_launch(void* const* d_in, const int* in_sizes, int n_in,
                              void* d_out, int out_size, void* d_ws, size_t ws_size,
                              hipStream_t stream) {
  const float* x = (const float*)d_in[0];
  const float* Wq = (const float*)d_in[1];
  const float* bq = (const float*)d_in[2];
  const float* Wk = (const float*)d_in[3];
  const float* bk = (const float*)d_in[4];
  const float* Wv = (const float*)d_in[5];
  const float* bv = (const float*)d_in[6];
  const float* gamma = (const float*)d_in[7];
  float* out = (float*)d_out;

  char* ws = (char*)d_ws;
  u16* Kt = (u16*)ws;                    // 512 KB: [2][4096][32]
  u16* Vb = (u16*)(ws + (512u << 10));   // 4 MB  : [2][256][4096]

  proj_kv<<<dim3(128), 256, 0, stream>>>(x, Wk, bk, Wv, bv, Kt, Vb);
  attn_kernel<<<dim3(512), 256, 0, stream>>>(x, Wq, bq, Kt, Vb, gamma, out);
}

// Round 7
// 171.184 us; speedup vs baseline: 1.8465x; 1.8465x over previous
//
#include <hip/hip_runtime.h>

typedef unsigned short u16;
typedef unsigned int u32;
typedef unsigned long long u64;
typedef float f32x4 __attribute__((ext_vector_type(4)));
typedef __bf16 bf16x8 __attribute__((ext_vector_type(8)));

// f32 -> bf16 round-to-nearest-even (scalar)
__device__ __forceinline__ u16 f2bf(float f) {
  unsigned u = __float_as_uint(f);
  unsigned r = u + 0x7fffu + ((u >> 16) & 1u);
  return (u16)(r >> 16);
}
// packed f32 pair -> 2x bf16 in one u32 (lo = first arg)
__device__ __forceinline__ u32 cvt_pk_bf16(float lo, float hi) {
  u32 r;
  asm("v_cvt_pk_bf16_f32 %0, %1, %2" : "=v"(r) : "v"(lo), "v"(hi));
  return r;
}
// hardware 2^x
__device__ __forceinline__ float exp2_hw(float x) {
  float r;
  asm("v_exp_f32 %0, %1" : "=v"(r) : "v"(x));
  return r;
}
__device__ __forceinline__ bf16x8 f32x8_to_bf16x8(float4 a, float4 b) {
  union { u32 u[4]; bf16x8 v; } t;
  t.u[0] = cvt_pk_bf16(a.x, a.y);
  t.u[1] = cvt_pk_bf16(a.z, a.w);
  t.u[2] = cvt_pk_bf16(b.x, b.y);
  t.u[3] = cvt_pk_bf16(b.z, b.w);
  return t.v;
}

// 1/sqrt(32) * log2(e)  — softmax scale folded with exp->exp2 conversion
#define QSCALE 0.25513936f

// ---------------------------------------------------------------------------
// proj_kernel: blocks 0..255 -> fused pooled K+V path, z-split by V-channel
// half (z=0: K + V ch 0..127; z=1: V ch 128..255) for 2x parallelism.
// blocks 256..767 -> Q path (round-3/5-verified LDS-staged MFMA).
// Layouts: Qb[b][t][32], Kt[b][s][32], Vb[b][ch][4096].
// ---------------------------------------------------------------------------
__global__ __launch_bounds__(256) void proj_kernel(
    const float* __restrict__ x, const float* __restrict__ Wq, const float* __restrict__ bq,
    const float* __restrict__ Wk, const float* __restrict__ bk, const float* __restrict__ Wv,
    const float* __restrict__ bv, u16* __restrict__ Qb, u16* __restrict__ Kt,
    u16* __restrict__ Vb) {
  __shared__ __align__(16) u16 smem[24576];  // 48KB: xt(32KB)+wq(16KB) | xs(32KB)
  const int tid = threadIdx.x;
  const int lane = tid & 63, w = tid >> 6;
  const int l15 = lane & 15, l4 = lane >> 4;
  const int bi = blockIdx.x;
  const f32x4 zero = {0.f, 0.f, 0.f, 0.f};

  if (bi >= 256) {
    // ================= Q path (verified, LDS-staged) =================
    u16* xt = smem;          // [64 t][256 c] bf16, swizzled
    u16* wq = smem + 16384;  // [32 oc][256 c] bf16, swizzled, pre-scaled
    const int j = bi - 256;
    const int b = j >> 8, tb = j & 255;
    const float* xp = x + (size_t)b * 256 * 16384 + tb * 64;

    for (int i = tid; i < 4096; i += 256) {
      int oc = i >> 7, c0 = (i & 127) * 2;
      float2 f = *reinterpret_cast<const float2*>(Wq + oc * 256 + c0);
      u32 pk = cvt_pk_bf16(f.x * QSCALE, f.y * QSCALE);
      *reinterpret_cast<u32*>((char*)wq + oc * 512 + (((c0 >> 3) ^ (oc & 7)) * 16) +
                              (c0 & 7) * 2) = pk;
    }
#pragma unroll
    for (int rr = 0; rr < 4; ++rr) {
      int c = rr * 64 + (tid >> 2);
      int tch = (tid & 3) * 16;
      const float* src = xp + (size_t)c * 16384 + tch;
#pragma unroll
      for (int u = 0; u < 4; ++u) {
        float4 f = *reinterpret_cast<const float4*>(src + u * 4);
        int t = tch + u * 4;
        *reinterpret_cast<u16*>((char*)xt + (t + 0) * 512 + (((c >> 3) ^ ((t + 0) & 7)) * 16) + (c & 7) * 2) = f2bf(f.x);
        *reinterpret_cast<u16*>((char*)xt + (t + 1) * 512 + (((c >> 3) ^ ((t + 1) & 7)) * 16) + (c & 7) * 2) = f2bf(f.y);
        *reinterpret_cast<u16*>((char*)xt + (t + 2) * 512 + (((c >> 3) ^ ((t + 2) & 7)) * 16) + (c & 7) * 2) = f2bf(f.z);
        *reinterpret_cast<u16*>((char*)xt + (t + 3) * 512 + (((c >> 3) ^ ((t + 3) & 7)) * 16) + (c & 7) * 2) = f2bf(f.w);
      }
    }
    __syncthreads();

    f32x4 acc[2] = {zero, zero};
    const int tl = w * 16 + l15;
#pragma unroll
    for (int k = 0; k < 8; ++k) {
      bf16x8 bf = *reinterpret_cast<const bf16x8*>((char*)xt + tl * 512 +
                                                   (((k * 4 + l4) ^ (tl & 7)) * 16));
#pragma unroll
      for (int m = 0; m < 2; ++m) {
        int oc = m * 16 + l15;
        bf16x8 af = *reinterpret_cast<const bf16x8*>((char*)wq + oc * 512 +
                                                     (((k * 4 + l4) ^ (oc & 7)) * 16));
        acc[m] = __builtin_amdgcn_mfma_f32_16x16x32_bf16(af, bf, acc[m], 0, 0, 0);
      }
    }
    const int t = tb * 64 + tl;
#pragma unroll
    for (int m = 0; m < 2; ++m) {
      int oc0 = m * 16 + l4 * 4;
      u32 p0 = cvt_pk_bf16(acc[m][0] + bq[oc0] * QSCALE, acc[m][1] + bq[oc0 + 1] * QSCALE);
      u32 p1 = cvt_pk_bf16(acc[m][2] + bq[oc0 + 2] * QSCALE, acc[m][3] + bq[oc0 + 3] * QSCALE);
      u16* dst = Qb + ((size_t)b * 16384 + t) * 32 + oc0;
      *reinterpret_cast<u32*>(dst) = p0;
      *reinterpret_cast<u32*>(dst + 2) = p1;
    }
  } else {
    // ================= fused K+V path, z-split =================
    u16* xs = smem;  // pooled [64 s][256 c] bf16, swizzled
    const int b = bi >> 7, r2 = bi & 127;
    const int sy = r2 >> 1, z = r2 & 1;
    const int mb = z * 8;  // V m-tile base (8 tiles = 128 channels per z)
    const float* xb = x + (size_t)b * 256 * 16384;

#pragma unroll
    for (int rr = 0; rr < 4; ++rr) {
      int c = rr * 64 + (tid >> 2);
      int f4base = (tid & 3) * 8;
      const float* r0 = xb + (size_t)c * 16384 + (size_t)sy * 256;
#pragma unroll
      for (int u = 0; u < 8; ++u) {
        int jj = f4base + u;
        float4 a = *reinterpret_cast<const float4*>(r0 + jj * 4);
        float4 d = *reinterpret_cast<const float4*>(r0 + 128 + jj * 4);
        float p0 = (a.x + a.y + d.x + d.y) * 0.25f;
        float p1 = (a.z + a.w + d.z + d.w) * 0.25f;
        int s0 = jj * 2;
        *reinterpret_cast<u16*>((char*)xs + (s0 + 0) * 512 + (((c >> 3) ^ ((s0 + 0) & 7)) * 16) + (c & 7) * 2) = f2bf(p0);
        *reinterpret_cast<u16*>((char*)xs + (s0 + 1) * 512 + (((c >> 3) ^ ((s0 + 1) & 7)) * 16) + (c & 7) * 2) = f2bf(p1);
      }
    }
    __syncthreads();

    f32x4 acc[10];
#pragma unroll
    for (int m = 0; m < 10; ++m) acc[m] = zero;
    const int sl = w * 16 + l15;
#pragma unroll
    for (int k = 0; k < 8; ++k) {
      bf16x8 bf = *reinterpret_cast<const bf16x8*>((char*)xs + sl * 512 +
                                                   (((k * 4 + l4) ^ (sl & 7)) * 16));
      if (z == 0) {
#pragma unroll
        for (int m = 0; m < 2; ++m) {
          const float* wr = Wk + (size_t)(m * 16 + l15) * 256 + k * 32 + l4 * 8;
          float4 fa = *reinterpret_cast<const float4*>(wr);
          float4 fb = *reinterpret_cast<const float4*>(wr + 4);
          acc[m] = __builtin_amdgcn_mfma_f32_16x16x32_bf16(f32x8_to_bf16x8(fa, fb), bf, acc[m], 0, 0, 0);
        }
      }
#pragma unroll
      for (int mm = 0; mm < 8; ++mm) {
        const float* wr = Wv + (size_t)((mb + mm) * 16 + l15) * 256 + k * 32 + l4 * 8;
        float4 fa = *reinterpret_cast<const float4*>(wr);
        float4 fb = *reinterpret_cast<const float4*>(wr + 4);
        acc[2 + mm] = __builtin_amdgcn_mfma_f32_16x16x32_bf16(f32x8_to_bf16x8(fa, fb), bf, acc[2 + mm], 0, 0, 0);
      }
    }
    if (z == 0) {
#pragma unroll
      for (int m = 0; m < 2; ++m) {
        int oc0 = m * 16 + l4 * 4;
        u32 p0 = cvt_pk_bf16(acc[m][0] + bk[oc0], acc[m][1] + bk[oc0 + 1]);
        u32 p1 = cvt_pk_bf16(acc[m][2] + bk[oc0 + 2], acc[m][3] + bk[oc0 + 3]);
        u16* dst = Kt + ((size_t)b * 4096 + sy * 64 + sl) * 32 + oc0;
        *reinterpret_cast<u32*>(dst) = p0;
        *reinterpret_cast<u32*>(dst + 2) = p1;
      }
    }
#pragma unroll
    for (int mm = 0; mm < 8; ++mm) {
#pragma unroll
      for (int r = 0; r < 4; ++r) {
        int oc = (mb + mm) * 16 + l4 * 4 + r;
        Vb[((size_t)b * 256 + oc) * 4096 + sy * 64 + sl] = f2bf(acc[2 + mm][r] + bv[oc]);
      }
    }
  }
}

// ---------------------------------------------------------------------------
// attn v7: 128-token x 128-channel blocks (halves V traffic per unit work),
// phase-reordered single-barrier iteration:
//   afr ds_reads (P[kt]) -> QK(kt+1)+exp+write P[kt+1]   [hides LDS latency]
//   -> PV(kt) -> vfr prefetch(kt+1) -> barrier.
// Wave: QK for ALL 128 toks x 16-key strip (8 MFMA, exp fused per-mt);
// PV for 64tok x 64ch quadrant (32 MFMA). b64 P-writes. VGPR ~210 by design.
// 512 blocks = 2/CU. XCD swizzle: one batch + contiguous tok-tiles per XCD.
// ---------------------------------------------------------------------------
__global__ __launch_bounds__(256, 2) void attn_kernel(
    const u16* __restrict__ Qb, const u16* __restrict__ Kt, const u16* __restrict__ Vb,
    const float* __restrict__ x, const float* __restrict__ gamma, float* __restrict__ out) {
  __shared__ __align__(16) u16 p_lds[2][128 * 64];  // 32KB (dbuf)
  __shared__ float lred[4][128];

  const int tid = threadIdx.x;
  const int lane = tid & 63, w = tid >> 6;
  const int l15 = lane & 15, l4 = lane >> 4;
  const int raw = blockIdx.x;               // 0..511
  const int xcd = raw & 7, loc = raw >> 3;  // loc 0..63
  const int b = xcd >> 2;
  const int H = loc & 1;                        // channel half of C=256
  const int tt = (xcd & 3) * 32 + (loc >> 1);   // tok-tile 0..127
  const int t0 = tt * 128;
  const int th = w >> 1, chh = w & 1;           // wave quadrant
  const int CHW = H * 128 + chh * 64;           // wave channel base

  const u16* Qp = Qb + (size_t)(b * 16384 + t0) * 32;
  const u16* Kp = Kt + (size_t)b * 4096 * 32;
  const u16* Vp = Vb + (size_t)b * 256 * 4096;

  // Q fragments (loop-invariant): B-operand col = tok = mt*16+l15, mt 0..7
  bf16x8 qfr[8];
#pragma unroll
  for (int mt = 0; mt < 8; ++mt)
    qfr[mt] = *reinterpret_cast<const bf16x8*>(Qp + (size_t)(mt * 16 + l15) * 32 + l4 * 8);

  const int key = w * 16 + l15;  // A-operand row for QK (wave's 16-key strip)
  const int pw_chunk = w * 2 + (l4 >> 1), pw_off = (l4 & 1) * 8;

  bf16x8 kfr = *reinterpret_cast<const bf16x8*>(Kp + (size_t)key * 32 + l4 * 8);
  bf16x8 vfr[2][4];
#pragma unroll
  for (int ks = 0; ks < 2; ++ks)
#pragma unroll
    for (int nt = 0; nt < 4; ++nt)
      vfr[ks][nt] = *reinterpret_cast<const bf16x8*>(
          Vp + (size_t)(CHW + nt * 16 + l15) * 4096 + ks * 32 + l4 * 8);

  f32x4 acc[4][4] = {};  // 64tok x 64ch quadrant
  float lsum[8] = {};
  const f32x4 zero = {0.f, 0.f, 0.f, 0.f};

  // ---- prologue: QK(0) + exp + write buf0 ----
#pragma unroll
  for (int mt = 0; mt < 8; ++mt) {
    f32x4 s = __builtin_amdgcn_mfma_f32_16x16x32_bf16(kfr, qfr[mt], zero, 0, 0, 0);
    float p0 = exp2_hw(fminf(s[0], 28.f)), p1 = exp2_hw(fminf(s[1], 28.f));
    float p2 = exp2_hw(fminf(s[2], 28.f)), p3 = exp2_hw(fminf(s[3], 28.f));
    lsum[mt] += (p0 + p1) + (p2 + p3);
    int tok = mt * 16 + l15;
    char* base = (char*)p_lds + tok * 128 + ((pw_chunk ^ (tok & 7)) * 16) + pw_off;
    *reinterpret_cast<u64*>(base) =
        (u64)cvt_pk_bf16(p0, p1) | ((u64)cvt_pk_bf16(p2, p3) << 32);
  }
  kfr = *reinterpret_cast<const bf16x8*>(Kp + (size_t)(64 + key) * 32 + l4 * 8);
  __syncthreads();

  for (int kt = 0; kt < 64; ++kt) {
    const int cur = kt & 1;
    // ---- afr ds_reads (P[kt]); latency hidden under QK+softmax below ----
    bf16x8 afr[2][4];
#pragma unroll
    for (int ks = 0; ks < 2; ++ks)
#pragma unroll
      for (int mt = 0; mt < 4; ++mt) {
        int tok = th * 64 + mt * 16 + l15;
        afr[ks][mt] = *reinterpret_cast<const bf16x8*>(
            (char*)p_lds + cur * 16384 + tok * 128 + (((ks * 4 + l4) ^ (tok & 7)) * 16));
      }
    if (kt < 63) {
      // ---- QK(kt+1) + exp + b64 write P[kt+1] (fused per-mt, sfr transient) ----
#pragma unroll
      for (int mt = 0; mt < 8; ++mt) {
        f32x4 s = __builtin_amdgcn_mfma_f32_16x16x32_bf16(kfr, qfr[mt], zero, 0, 0, 0);
        float p0 = exp2_hw(fminf(s[0], 28.f)), p1 = exp2_hw(fminf(s[1], 28.f));
        float p2 = exp2_hw(fminf(s[2], 28.f)), p3 = exp2_hw(fminf(s[3], 28.f));
        lsum[mt] += (p0 + p1) + (p2 + p3);
        int tok = mt * 16 + l15;
        char* base = (char*)p_lds + (cur ^ 1) * 16384 + tok * 128 +
                     ((pw_chunk ^ (tok & 7)) * 16) + pw_off;
        *reinterpret_cast<u64*>(base) =
            (u64)cvt_pk_bf16(p0, p1) | ((u64)cvt_pk_bf16(p2, p3) << 32);
      }
      kfr = *reinterpret_cast<const bf16x8*>(
          Kp + (size_t)(((kt < 62) ? kt + 2 : 63) * 64 + key) * 32 + l4 * 8);
    }
    // ---- PV(kt): acc += P * V^T ----
#pragma unroll
    for (int ks = 0; ks < 2; ++ks)
#pragma unroll
      for (int mt = 0; mt < 4; ++mt)
#pragma unroll
        for (int nt = 0; nt < 4; ++nt)
          acc[mt][nt] = __builtin_amdgcn_mfma_f32_16x16x32_bf16(afr[ks][mt], vfr[ks][nt],
                                                               acc[mt][nt], 0, 0, 0);
    // ---- vfr prefetch (kt+1); full next-iter window to land ----
    if (kt < 63) {
#pragma unroll
      for (int ks = 0; ks < 2; ++ks)
#pragma unroll
        for (int nt = 0; nt < 4; ++nt)
          vfr[ks][nt] = *reinterpret_cast<const bf16x8*>(
              Vp + (size_t)(CHW + nt * 16 + l15) * 4096 + (kt + 1) * 64 + ks * 32 + l4 * 8);
    }
    __syncthreads();
  }

  // ---- row sums: reduce over l4 groups, publish per-wave strip sums ----
#pragma unroll
  for (int mt = 0; mt < 8; ++mt) {
    lsum[mt] += __shfl_xor(lsum[mt], 16, 64);
    lsum[mt] += __shfl_xor(lsum[mt], 32, 64);
  }
  if (l4 == 0) {
#pragma unroll
    for (int mt = 0; mt < 8; ++mt) lred[w][mt * 16 + l15] = lsum[mt];
  }
  __syncthreads();

  const float g = gamma[0];
  float linv[16];
#pragma unroll
  for (int mt = 0; mt < 4; ++mt)
#pragma unroll
    for (int r = 0; r < 4; ++r) {
      int tok = th * 64 + mt * 16 + l4 * 4 + r;
      linv[mt * 4 + r] = 1.0f / (lred[0][tok] + lred[1][tok] + lred[2][tok] + lred[3][tok]);
    }
  // ---- epilogue: out = gamma * acc / l + x ----
#pragma unroll
  for (int mt = 0; mt < 4; ++mt) {
#pragma unroll
    for (int nt = 0; nt < 4; ++nt) {
      int ch = CHW + nt * 16 + l15;
      size_t idx = ((size_t)(b * 256 + ch)) * 16384 + t0 + th * 64 + mt * 16 + l4 * 4;
      float4 xr = *reinterpret_cast<const float4*>(x + idx);
      float4 o;
      o.x = g * acc[mt][nt][0] * linv[mt * 4 + 0] + xr.x;
      o.y = g * acc[mt][nt][1] * linv[mt * 4 + 1] + xr.y;
      o.z = g * acc[mt][nt][2] * linv[mt * 4 + 2] + xr.z;
      o.w = g * acc[mt][nt][3] * linv[mt * 4 + 3] + xr.w;
      *reinterpret_cast<float4*>(out + idx) = o;
    }
  }
}

// ---------------------------------------------------------------------------
extern "C" void kernel_launch(void* const* d_in, const int* in_sizes, int n_in,
                              void* d_out, int out_size, void* d_ws, size_t ws_size,
                              hipStream_t stream) {
  const float* x = (const float*)d_in[0];
  const float* Wq = (const float*)d_in[1];
  const float* bq = (const float*)d_in[2];
  const float* Wk = (const float*)d_in[3];
  const float* bk = (const float*)d_in[4];
  const float* Wv = (const float*)d_in[5];
  const float* bv = (const float*)d_in[6];
  const float* gamma = (const float*)d_in[7];
  float* out = (float*)d_out;

  char* ws = (char*)d_ws;
  u16* Qb = (u16*)ws;                                // 2 MB  : [2][16384][32]
  u16* Kt = (u16*)(ws + (2u << 20));                 // 512 KB: [2][4096][32]
  u16* Vb = (u16*)(ws + (2u << 20) + (512u << 10));  // 4 MB  : [2][256][4096]

  proj_kernel<<<dim3(768), 256, 0, stream>>>(x, Wq, bq, Wk, bk, Wv, bv, Qb, Kt, Vb);
  attn_kernel<<<dim3(512), 256, 0, stream>>>(Qb, Kt, Vb, x, gamma, out);
}